// Round 3
// baseline (13849.046 us; speedup 1.0000x reference)
//
#include <hip/hip_runtime.h>
#include <hip/hip_bf16.h>

typedef __bf16 bf16;
typedef __bf16 bf16x8 __attribute__((ext_vector_type(8)));
typedef float  floatx4 __attribute__((ext_vector_type(4)));

#define NWG 56          // 896/16 column-slices for the scan

// ---------------- workspace layout (bytes) ----------------
static constexpr size_t CT_OFF  = 0;
static constexpr size_t HB_OFF  = 256;
static constexpr size_t WBF_OFF = 256 + 114688;                 // 114,944
static constexpr size_t GX_OFF  = WBF_OFF + 13565952;           // 13,680,896
static constexpr size_t HSX_OFF = GX_OFF + 176160768;           // 189,841,664
// total = 248,561,920 bytes

static constexpr size_t W_IH_E = 2688 * 896;   // bf16 element offsets inside wbf
static constexpr size_t W_HH_E = 2688 * 896;
static constexpr size_t W_F1_E = 1024 * 896;

__device__ __forceinline__ float sigm(float x)      { return 1.f / (1.f + __expf(-x)); }
__device__ __forceinline__ float fast_tanh(float x) { return 2.f / (1.f + __expf(-2.f * x)) - 1.f; }

// ---------------- f32 -> bf16 conversion (8 elems / thread), exact grids ----------------
__global__ __launch_bounds__(256) void k_cvt(const float* __restrict__ src,
                                             bf16* __restrict__ dst)
{
    const int s = blockIdx.x * 256 + threadIdx.x;
    const float4 a = ((const float4*)src)[s * 2 + 0];
    const float4 b = ((const float4*)src)[s * 2 + 1];
    bf16x8 v;
    v[0] = (bf16)a.x; v[1] = (bf16)a.y; v[2] = (bf16)a.z; v[3] = (bf16)a.w;
    v[4] = (bf16)b.x; v[5] = (bf16)b.y; v[6] = (bf16)b.z; v[7] = (bf16)b.w;
    ((bf16x8*)dst)[s] = v;
}

// ---------------- embed + concat (f32 in, bf16 out) ----------------
__global__ __launch_bounds__(256) void k_embed(const int* __restrict__ samp,
                                               const float* __restrict__ cnd,
                                               const float* __restrict__ emb,
                                               bf16* __restrict__ x)
{
    const int s = blockIdx.x * 256 + threadIdx.x;   // 8-elem segment id; 112 segs/row
    const int r = s / 112;
    const int c = s % 112;
    const float* src;
    if (c < 32) src = emb + samp[r] * 256 + c * 8;
    else        src = cnd + (long)r * 640 + (c - 32) * 8;
    const float4 a = ((const float4*)src)[0];
    const float4 b = ((const float4*)src)[1];
    bf16x8 v;
    v[0] = (bf16)a.x; v[1] = (bf16)a.y; v[2] = (bf16)a.z; v[3] = (bf16)a.w;
    v[4] = (bf16)b.x; v[5] = (bf16)b.y; v[6] = (bf16)b.z; v[7] = (bf16)b.w;
    *(bf16x8*)(x + (long)r * 896 + c * 8) = v;
}

// ---------------- GEMM: C[M,N] = A[M,K] @ Bw[N,K]^T + bias(f32), 128x128 tile, 4 waves ----------
// GXMODE=1 writes C at ((t*16+b)*N + n) with r = b*2048 + t  (scan-friendly gx layout)
// OUTF32=1 writes float output (d_out is f32 per reference dtype), else bf16
template <int RELU, int GXMODE, int OUTF32>
__global__ __launch_bounds__(256, 2) void gemm_bt(const bf16* __restrict__ A,
                                                  const bf16* __restrict__ Bw,
                                                  const float* __restrict__ bias,
                                                  void* __restrict__ Cv,
                                                  int M, int N, int K)
{
    __shared__ bf16 As[128 * 40];   // +8 pad elems per 32-col row: conflict-free frag reads
    __shared__ bf16 Bs[128 * 40];

    const int tid  = threadIdx.x;
    const int lane = tid & 63;
    const int wv   = tid >> 6;      // 0..3
    const int wm   = wv >> 1;       // 0..1
    const int wn   = wv & 1;        // 0..1
    const int n16  = lane & 15;
    const int quad = lane >> 4;
    const int tm   = blockIdx.y * 128;
    const int tn   = blockIdx.x * 128;

    floatx4 acc[4][4] = {};

    const int s0 = tid, s1 = tid + 256;       // 512 segs per tile (128 rows x 4 segs)
    const int r0 = s0 >> 2, c0 = s0 & 3;
    const int r1 = s1 >> 2, c1 = s1 & 3;

    const int KT = K >> 5;
    for (int kt = 0; kt < KT; ++kt) {
        const int k0 = kt * 32;
        bf16x8 a0 = *(const bf16x8*)(A  + (long)(tm + r0) * K + k0 + c0 * 8);
        bf16x8 a1 = *(const bf16x8*)(A  + (long)(tm + r1) * K + k0 + c1 * 8);
        bf16x8 b0 = *(const bf16x8*)(Bw + (long)(tn + r0) * K + k0 + c0 * 8);
        bf16x8 b1 = *(const bf16x8*)(Bw + (long)(tn + r1) * K + k0 + c1 * 8);
        __syncthreads();
        *(bf16x8*)(As + r0 * 40 + c0 * 8) = a0;
        *(bf16x8*)(As + r1 * 40 + c1 * 8) = a1;
        *(bf16x8*)(Bs + r0 * 40 + c0 * 8) = b0;
        *(bf16x8*)(Bs + r1 * 40 + c1 * 8) = b1;
        __syncthreads();

        bf16x8 af[4], bfj[4];
#pragma unroll
        for (int i = 0; i < 4; ++i)
            af[i] = *(const bf16x8*)(As + (wm * 64 + i * 16 + n16) * 40 + quad * 8);
#pragma unroll
        for (int j = 0; j < 4; ++j)
            bfj[j] = *(const bf16x8*)(Bs + (wn * 64 + j * 16 + n16) * 40 + quad * 8);
#pragma unroll
        for (int i = 0; i < 4; ++i)
#pragma unroll
            for (int j = 0; j < 4; ++j)
                acc[i][j] = __builtin_amdgcn_mfma_f32_16x16x32_bf16(af[i], bfj[j], acc[i][j], 0, 0, 0);
    }

#pragma unroll
    for (int j = 0; j < 4; ++j) {
        const int c = tn + wn * 64 + j * 16 + n16;
        const float bv = bias[c];
#pragma unroll
        for (int i = 0; i < 4; ++i) {
            const int rbase = tm + wm * 64 + i * 16 + quad * 4;
#pragma unroll
            for (int rr = 0; rr < 4; ++rr) {
                float v = acc[i][j][rr] + bv;
                if (RELU) v = fmaxf(v, 0.f);
                const int r = rbase + rr;
                long oidx;
                if (GXMODE) { const int tt = r & 2047, bb = r >> 11; oidx = (long)(tt * 16 + bb) * N + c; }
                else        { oidx = (long)r * N + c; }
                if (OUTF32) ((float*)Cv)[oidx] = v;
                else        ((bf16*)Cv)[oidx]  = (bf16)v;
            }
        }
    }
}

// ---------------- GRU scan: 56 persistent WGs x 192 thr; wave g computes gate g for 16 cols ----
// W_hh slice (bf16) in VGPRs; h carried f32 in hbuf, rounded to bf16 only as MFMA input.
__global__ __launch_bounds__(192, 1) void gru_scan(const bf16* __restrict__ Whh,
                                                   const float* __restrict__ bhh,
                                                   const bf16* __restrict__ gx,
                                                   bf16* __restrict__ hs,
                                                   float* __restrict__ hbuf,
                                                   unsigned int* __restrict__ ctr)
{
    __shared__ bf16  hst[16 * 904];     // h (bf16) stage, padded stride 904
    __shared__ float gacc[3][16][16];   // [gate][batch][col]
    __shared__ float bhs[3][16];

    const int tid  = threadIdx.x;
    const int wv   = tid >> 6;          // 0..2 = gate (r,z,n)
    const int lane = tid & 63;
    const int n16  = lane & 15;
    const int quad = lane >> 4;
    const int col0 = blockIdx.x * 16;

    // one-time: weight slice -> registers  (B-frag: n=lane&15 row of W, k=quad*8+j)
    bf16x8 wf[28];
    {
        const bf16* wrow = Whh + (long)(wv * 896 + col0 + n16) * 896;
#pragma unroll
        for (int kt = 0; kt < 28; ++kt)
            wf[kt] = *(const bf16x8*)(wrow + kt * 32 + quad * 8);
    }
    if (tid < 48) bhs[tid / 16][tid % 16] = bhh[(tid / 16) * 896 + col0 + (tid % 16)];
    __syncthreads();

    for (int t = 0; t < 2048; ++t) {
        const int p = t & 1;
        const float* hsrc = hbuf + p * (16 * 896);
        float*       hdst = hbuf + (1 - p) * (16 * 896);

        // this step's gx slice (threads 0..127 handle 2 cols each)
        float gxv[6];
        const int b  = tid >> 3;
        const int c2 = (tid & 7) * 2;
        if (tid < 128) {
            const bf16* g0 = gx + (long)(t * 16 + b) * 2688 + col0 + c2;
#pragma unroll
            for (int g = 0; g < 3; ++g) {
                gxv[g * 2 + 0] = (float)g0[g * 896 + 0];
                gxv[g * 2 + 1] = (float)g0[g * 896 + 1];
            }
        }

        // stage h[16][896] f32 -> bf16 LDS (batched loads)
        {
            float4 ta[9], tb[9];
#pragma unroll
            for (int it = 0; it < 9; ++it) {
                const int s = tid + it * 192;
                const float* sp = hsrc + (s / 112) * 896 + (s % 112) * 8;
                ta[it] = ((const float4*)sp)[0];
                tb[it] = ((const float4*)sp)[1];
            }
            float4 tc, td;
            if (tid < 64) {
                const int s = tid + 1728;
                const float* sp = hsrc + (s / 112) * 896 + (s % 112) * 8;
                tc = ((const float4*)sp)[0];
                td = ((const float4*)sp)[1];
            }
#pragma unroll
            for (int it = 0; it < 9; ++it) {
                const int s = tid + it * 192;
                bf16x8 v;
                v[0] = (bf16)ta[it].x; v[1] = (bf16)ta[it].y; v[2] = (bf16)ta[it].z; v[3] = (bf16)ta[it].w;
                v[4] = (bf16)tb[it].x; v[5] = (bf16)tb[it].y; v[6] = (bf16)tb[it].z; v[7] = (bf16)tb[it].w;
                *(bf16x8*)(hst + (s / 112) * 904 + (s % 112) * 8) = v;
            }
            if (tid < 64) {
                const int s = tid + 1728;
                bf16x8 v;
                v[0] = (bf16)tc.x; v[1] = (bf16)tc.y; v[2] = (bf16)tc.z; v[3] = (bf16)tc.w;
                v[4] = (bf16)td.x; v[5] = (bf16)td.y; v[6] = (bf16)td.z; v[7] = (bf16)td.w;
                *(bf16x8*)(hst + (s / 112) * 904 + (s % 112) * 8) = v;
            }
        }
        __syncthreads();

        // gh(gate wv) = h @ Whh_slice^T : 28 MFMAs, A-frag from LDS, B-frag from registers
        floatx4 acc = {0.f, 0.f, 0.f, 0.f};
#pragma unroll
        for (int kt = 0; kt < 28; ++kt) {
            bf16x8 af = *(const bf16x8*)(hst + n16 * 904 + kt * 32 + quad * 8);
            acc = __builtin_amdgcn_mfma_f32_16x16x32_bf16(af, wf[kt], acc, 0, 0, 0);
        }
#pragma unroll
        for (int r = 0; r < 4; ++r) gacc[wv][quad * 4 + r][n16] = acc[r];
        __syncthreads();

        // gate nonlinearity + h update (threads 0..127, 2 cols each); h carried in f32
        if (tid < 128) {
#pragma unroll
            for (int u = 0; u < 2; ++u) {
                const int c = c2 + u;
                const float ghr = gacc[0][b][c] + bhs[0][c];
                const float ghz = gacc[1][b][c] + bhs[1][c];
                const float ghn = gacc[2][b][c] + bhs[2][c];
                const float rg = sigm(gxv[0 + u] + ghr);
                const float zg = sigm(gxv[2 + u] + ghz);
                const float ng = fast_tanh(gxv[4 + u] + rg * ghn);
                const float hold = hsrc[b * 896 + col0 + c];
                const float hnew = (1.f - zg) * ng + zg * hold;
                hdst[b * 896 + col0 + c] = hnew;
                hs[((long)b * 2048 + t) * 896 + col0 + c] = (bf16)hnew;
            }
        }

        // grid barrier (device-scope): release h writes, arrive, spin, acquire
        __syncthreads();
        if (tid == 0) {
            __threadfence();
            __hip_atomic_fetch_add(ctr, 1u, __ATOMIC_RELAXED, __HIP_MEMORY_SCOPE_AGENT);
            const unsigned tgt = (unsigned)NWG * (unsigned)(t + 1);
            while (__hip_atomic_load(ctr, __ATOMIC_RELAXED, __HIP_MEMORY_SCOPE_AGENT) < tgt)
                __builtin_amdgcn_s_sleep(2);
            __threadfence();
        }
        __syncthreads();
    }
}

extern "C" void kernel_launch(void* const* d_in, const int* in_sizes, int n_in,
                              void* d_out, int out_size, void* d_ws, size_t ws_size,
                              hipStream_t stream)
{
    const int*   samp = (const int*)d_in[0];
    const float* cnd  = (const float*)d_in[1];
    const float* emb  = (const float*)d_in[2];
    const float* Wih  = (const float*)d_in[3];
    const float* bih  = (const float*)d_in[4];
    const float* Whh  = (const float*)d_in[5];
    const float* bhh  = (const float*)d_in[6];
    const float* fc1w = (const float*)d_in[7];
    const float* fc1b = (const float*)d_in[8];
    const float* fc2w = (const float*)d_in[9];
    const float* fc2b = (const float*)d_in[10];

    char* ws = (char*)d_ws;
    unsigned int* ctr = (unsigned int*)(ws + CT_OFF);
    float* hbuf = (float*)(ws + HB_OFF);
    bf16*  wbf  = (bf16*)(ws + WBF_OFF);
    bf16*  gx   = (bf16*)(ws + GX_OFF);
    bf16*  hs   = (bf16*)(ws + HSX_OFF);
    bf16*  x    = (bf16*)(ws + HSX_OFF);   // x dead before hs is written (disjoint lifetime)
    bf16*  h1   = (bf16*)(ws + GX_OFF);    // h1 aliases gx (dead after scan)

    bf16* wih_bf = wbf;
    bf16* whh_bf = wbf + W_IH_E;
    bf16* fc1_bf = whh_bf + W_HH_E;
    bf16* fc2_bf = fc1_bf + W_F1_E;

    (void)hipMemsetAsync(ctr, 0, 256, stream);                  // barrier counter
    (void)hipMemsetAsync(hbuf, 0, 2 * 16 * 896 * 4, stream);    // h0 = 0 (f32)

    // 0) weights f32 -> bf16   (grids exact: n/8/256)
    k_cvt<<<1176, 256, 0, stream>>>(Wih,  wih_bf);
    k_cvt<<<1176, 256, 0, stream>>>(Whh,  whh_bf);
    k_cvt<<< 448, 256, 0, stream>>>(fc1w, fc1_bf);
    k_cvt<<< 512, 256, 0, stream>>>(fc2w, fc2_bf);

    // 1) x = concat(emb[sample], cnd)  f32->bf16   [32768, 896]
    k_embed<<<14336, 256, 0, stream>>>(samp, cnd, emb, x);
    // 2) gx = x @ W_ih^T + b_ih  -> [T][B][2688] layout (bf16)
    gemm_bt<0, 1, 0><<<dim3(21, 256), 256, 0, stream>>>(x, wih_bf, bih, gx, 32768, 2688, 896);
    // 3) sequential GRU scan -> hs [B][T][896] (bf16)
    gru_scan<<<NWG, 192, 0, stream>>>(whh_bf, bhh, gx, hs, hbuf, ctr);
    // 4) h1 = relu(hs @ fc1_w^T + fc1_b)           [32768, 1024] (bf16)
    gemm_bt<1, 0, 0><<<dim3(8, 256), 256, 0, stream>>>(hs, fc1_bf, fc1b, h1, 32768, 1024, 896);
    // 5) out = h1 @ fc2_w^T + fc2_b                [32768, 1024] -> FLOAT32 d_out
    gemm_bt<0, 0, 1><<<dim3(8, 256), 256, 0, stream>>>(h1, fc2_bf, fc2b, d_out, 32768, 1024, 1024);
}

// Round 4
// 11893.871 us; speedup vs baseline: 1.1644x; 1.1644x over previous
//
#include <hip/hip_runtime.h>
#include <hip/hip_bf16.h>

typedef __bf16 bf16;
typedef __bf16 bf16x2 __attribute__((ext_vector_type(2)));
typedef __bf16 bf16x8 __attribute__((ext_vector_type(8)));
typedef float  floatx4 __attribute__((ext_vector_type(4)));

#define NWG 56          // 896/16 column-slices for the scan

// ---------------- workspace layout (bytes) ----------------
// flags: 56 x 128B lines                        = 8,192
// hbuf : bf16 [2][56][16][16]                   = 57,344
// wbf  : bf16 Wih+Whh+fc1+fc2                   = 13,565,952
// gx   : [T][B][2688] bf16 (h1 aliases after)   = 176,160,768
// hs/x : [32768][896] bf16                      = 58,720,256
static constexpr size_t FL_OFF  = 0;
static constexpr size_t HB_OFF  = 8192;
static constexpr size_t WBF_OFF = 65536;
static constexpr size_t GX_OFF  = WBF_OFF + 13565952;           // 13,631,488
static constexpr size_t HSX_OFF = GX_OFF + 176160768;           // 189,792,256
// total ~248.5 MB (round 1 proved >= ~302 MB mapped)

static constexpr size_t W_IH_E = 2688 * 896;
static constexpr size_t W_HH_E = 2688 * 896;
static constexpr size_t W_F1_E = 1024 * 896;

__device__ __forceinline__ float sigm(float x)      { return 1.f / (1.f + __expf(-x)); }
__device__ __forceinline__ float fast_tanh(float x) { return 2.f / (1.f + __expf(-2.f * x)) - 1.f; }

// ---------------- f32 -> bf16 conversion (8 elems / thread), exact grids ----------------
__global__ __launch_bounds__(256) void k_cvt(const float* __restrict__ src,
                                             bf16* __restrict__ dst)
{
    const int s = blockIdx.x * 256 + threadIdx.x;
    const float4 a = ((const float4*)src)[s * 2 + 0];
    const float4 b = ((const float4*)src)[s * 2 + 1];
    bf16x8 v;
    v[0] = (bf16)a.x; v[1] = (bf16)a.y; v[2] = (bf16)a.z; v[3] = (bf16)a.w;
    v[4] = (bf16)b.x; v[5] = (bf16)b.y; v[6] = (bf16)b.z; v[7] = (bf16)b.w;
    ((bf16x8*)dst)[s] = v;
}

// ---------------- embed + concat (f32 in, bf16 out) ----------------
__global__ __launch_bounds__(256) void k_embed(const int* __restrict__ samp,
                                               const float* __restrict__ cnd,
                                               const float* __restrict__ emb,
                                               bf16* __restrict__ x)
{
    const int s = blockIdx.x * 256 + threadIdx.x;   // 8-elem segment id; 112 segs/row
    const int r = s / 112;
    const int c = s % 112;
    const float* src;
    if (c < 32) src = emb + samp[r] * 256 + c * 8;
    else        src = cnd + (long)r * 640 + (c - 32) * 8;
    const float4 a = ((const float4*)src)[0];
    const float4 b = ((const float4*)src)[1];
    bf16x8 v;
    v[0] = (bf16)a.x; v[1] = (bf16)a.y; v[2] = (bf16)a.z; v[3] = (bf16)a.w;
    v[4] = (bf16)b.x; v[5] = (bf16)b.y; v[6] = (bf16)b.z; v[7] = (bf16)b.w;
    *(bf16x8*)(x + (long)r * 896 + c * 8) = v;
}

// ---------------- GEMM: C[M,N] = A[M,K] @ Bw[N,K]^T + bias(f32), 128x128 tile, 4 waves ----------
template <int RELU, int GXMODE, int OUTF32>
__global__ __launch_bounds__(256, 2) void gemm_bt(const bf16* __restrict__ A,
                                                  const bf16* __restrict__ Bw,
                                                  const float* __restrict__ bias,
                                                  void* __restrict__ Cv,
                                                  int M, int N, int K)
{
    __shared__ bf16 As[128 * 40];
    __shared__ bf16 Bs[128 * 40];

    const int tid  = threadIdx.x;
    const int lane = tid & 63;
    const int wv   = tid >> 6;
    const int wm   = wv >> 1;
    const int wn   = wv & 1;
    const int n16  = lane & 15;
    const int quad = lane >> 4;
    const int tm   = blockIdx.y * 128;
    const int tn   = blockIdx.x * 128;

    floatx4 acc[4][4] = {};

    const int s0 = tid, s1 = tid + 256;
    const int r0 = s0 >> 2, c0 = s0 & 3;
    const int r1 = s1 >> 2, c1 = s1 & 3;

    const int KT = K >> 5;
    for (int kt = 0; kt < KT; ++kt) {
        const int k0 = kt * 32;
        bf16x8 a0 = *(const bf16x8*)(A  + (long)(tm + r0) * K + k0 + c0 * 8);
        bf16x8 a1 = *(const bf16x8*)(A  + (long)(tm + r1) * K + k0 + c1 * 8);
        bf16x8 b0 = *(const bf16x8*)(Bw + (long)(tn + r0) * K + k0 + c0 * 8);
        bf16x8 b1 = *(const bf16x8*)(Bw + (long)(tn + r1) * K + k0 + c1 * 8);
        __syncthreads();
        *(bf16x8*)(As + r0 * 40 + c0 * 8) = a0;
        *(bf16x8*)(As + r1 * 40 + c1 * 8) = a1;
        *(bf16x8*)(Bs + r0 * 40 + c0 * 8) = b0;
        *(bf16x8*)(Bs + r1 * 40 + c1 * 8) = b1;
        __syncthreads();

        bf16x8 af[4], bfj[4];
#pragma unroll
        for (int i = 0; i < 4; ++i)
            af[i] = *(const bf16x8*)(As + (wm * 64 + i * 16 + n16) * 40 + quad * 8);
#pragma unroll
        for (int j = 0; j < 4; ++j)
            bfj[j] = *(const bf16x8*)(Bs + (wn * 64 + j * 16 + n16) * 40 + quad * 8);
#pragma unroll
        for (int i = 0; i < 4; ++i)
#pragma unroll
            for (int j = 0; j < 4; ++j)
                acc[i][j] = __builtin_amdgcn_mfma_f32_16x16x32_bf16(af[i], bfj[j], acc[i][j], 0, 0, 0);
    }

#pragma unroll
    for (int j = 0; j < 4; ++j) {
        const int c = tn + wn * 64 + j * 16 + n16;
        const float bv = bias[c];
#pragma unroll
        for (int i = 0; i < 4; ++i) {
            const int rbase = tm + wm * 64 + i * 16 + quad * 4;
#pragma unroll
            for (int rr = 0; rr < 4; ++rr) {
                float v = acc[i][j][rr] + bv;
                if (RELU) v = fmaxf(v, 0.f);
                const int r = rbase + rr;
                long oidx;
                if (GXMODE) { const int tt = r & 2047, bb = r >> 11; oidx = (long)(tt * 16 + bb) * N + c; }
                else        { oidx = (long)r * N + c; }
                if (OUTF32) ((float*)Cv)[oidx] = v;
                else        ((bf16*)Cv)[oidx]  = (bf16)v;
            }
        }
    }
}

// ---------------- GRU scan: 56 persistent WGs x 192 thr ----------------
// wave g = gate g for this WG's 16 cols; W_hh slice in VGPRs (28 x bf16x8).
// h state: f32 regs in threads 64..191 (2 cols each). Broadcast: bf16 hbuf[2][56][256].
// Barrier: per-WG flag line (128B apart), wave-0 parallel spin + __all.
__global__ __launch_bounds__(192, 1) void gru_scan(const bf16* __restrict__ Whh,
                                                   const float* __restrict__ bhh,
                                                   const bf16* __restrict__ gx,
                                                   bf16* __restrict__ hs,
                                                   bf16* __restrict__ hbuf,
                                                   unsigned int* __restrict__ flags)
{
    __shared__ bf16  hst[16 * 904];     // [b][k] stage, padded stride 904 (conflict-free)
    __shared__ float gacc[3][16][16];   // [gate][batch][col]
    __shared__ float bhs[3][16];

    const int tid  = threadIdx.x;
    const int wv   = tid >> 6;          // 0..2 = gate (r,z,n)
    const int lane = tid & 63;
    const int n16  = lane & 15;
    const int quad = lane >> 4;
    const int wg   = blockIdx.x;
    const int col0 = wg * 16;

    // one-time: weight slice -> registers  (B-frag: n=lane&15 row of W, k=quad*8+j)
    bf16x8 wf[28];
    {
        const bf16* wrow = Whh + (long)(wv * 896 + col0 + n16) * 896;
#pragma unroll
        for (int kt = 0; kt < 28; ++kt)
            wf[kt] = *(const bf16x8*)(wrow + kt * 32 + quad * 8);
    }
    if (tid < 48) bhs[tid / 16][tid % 16] = bhh[(tid / 16) * 896 + col0 + (tid % 16)];

    // update-thread state (threads 64..191): 2 cols each, h carried in f32
    const int u0 = tid - 64;
    const int b  = u0 >> 3;
    const int c2 = (u0 & 7) * 2;
    float hl0 = 0.f, hl1 = 0.f;
    float gxv[6];
    if (tid >= 64) {
        const bf16* g0 = gx + (long)(0 * 16 + b) * 2688 + col0 + c2;
#pragma unroll
        for (int g = 0; g < 3; ++g) {
            gxv[g * 2 + 0] = (float)g0[g * 896 + 0];
            gxv[g * 2 + 1] = (float)g0[g * 896 + 1];
        }
    }
    __syncthreads();

    for (int t = 0; t < 2048; ++t) {
        const bf16* hb_cur  = hbuf + (t & 1) * (56 * 256);
        bf16*       hb_next = hbuf + ((t + 1) & 1) * (56 * 256);

        // 1) wave 0: parallel spin until all 56 WGs have published h_t
        if (tid < 64) {
            if (t > 0) {
                for (;;) {
                    unsigned f = (lane < NWG)
                        ? __hip_atomic_load(flags + lane * 32, __ATOMIC_RELAXED, __HIP_MEMORY_SCOPE_AGENT)
                        : 0xFFFFFFFFu;
                    if (__all(f >= (unsigned)t)) break;
                    __builtin_amdgcn_s_sleep(1);
                }
            }
            __threadfence();   // acquire: invalidate stale cache lines
        }
        __syncthreads();

        // 2) stage hbuf[t&1] (28KB, [ct][b][half]) -> hst[b][k]  (1792 bf16x8 segs)
        {
            bf16x8 seg[9];
#pragma unroll
            for (int it = 0; it < 9; ++it)
                seg[it] = *(const bf16x8*)(hb_cur + (tid + it * 192) * 8);
            bf16x8 segl;
            if (tid < 64) segl = *(const bf16x8*)(hb_cur + (1728 + tid) * 8);
#pragma unroll
            for (int it = 0; it < 9; ++it) {
                const int s = tid + it * 192;
                const int ct = s >> 5, rem = s & 31, bb = rem >> 1, hf = rem & 1;
                *(bf16x8*)(hst + bb * 904 + ct * 16 + hf * 8) = seg[it];
            }
            if (tid < 64) {
                const int s = 1728 + tid;
                const int ct = s >> 5, rem = s & 31, bb = rem >> 1, hf = rem & 1;
                *(bf16x8*)(hst + bb * 904 + ct * 16 + hf * 8) = segl;
            }
        }
        __syncthreads();

        // 3) gh(gate wv) = h @ Whh_slice^T : 28 MFMAs
        floatx4 acc = {0.f, 0.f, 0.f, 0.f};
#pragma unroll
        for (int kt = 0; kt < 28; ++kt) {
            bf16x8 af = *(const bf16x8*)(hst + n16 * 904 + kt * 32 + quad * 8);
            acc = __builtin_amdgcn_mfma_f32_16x16x32_bf16(af, wf[kt], acc, 0, 0, 0);
        }
#pragma unroll
        for (int r = 0; r < 4; ++r) gacc[wv][quad * 4 + r][n16] = acc[r];
        __syncthreads();

        // 4) gate nonlinearity + h update (threads 64..191, 2 cols each)
        if (tid >= 64) {
            float hn[2];
            const float hold[2] = { hl0, hl1 };
#pragma unroll
            for (int u = 0; u < 2; ++u) {
                const int c = c2 + u;
                const float ghr = gacc[0][b][c] + bhs[0][c];
                const float ghz = gacc[1][b][c] + bhs[1][c];
                const float ghn = gacc[2][b][c] + bhs[2][c];
                const float rg = sigm(gxv[0 + u] + ghr);
                const float zg = sigm(gxv[2 + u] + ghz);
                const float ng = fast_tanh(gxv[4 + u] + rg * ghn);
                hn[u] = (1.f - zg) * ng + zg * hold[u];
            }
            hl0 = hn[0]; hl1 = hn[1];
            bf16x2 hv; hv[0] = (bf16)hn[0]; hv[1] = (bf16)hn[1];
            *(bf16x2*)(hb_next + wg * 256 + b * 16 + c2) = hv;
            *(bf16x2*)(hs + ((long)b * 2048 + t) * 896 + col0 + c2) = hv;
        }
        __syncthreads();

        // 5) publish h_{t+1}: release own flag (private cacheline, no RMW contention)
        if (tid == 0) {
            __threadfence();
            __hip_atomic_store(flags + wg * 32, (unsigned)(t + 1),
                               __ATOMIC_RELEASE, __HIP_MEMORY_SCOPE_AGENT);
        }

        // 6) prefetch gx for t+1 (waves 1-2; overlaps next iteration's wave-0 spin)
        if (tid >= 64) {
            const int tn_ = (t + 1 < 2048) ? (t + 1) : 2047;
            const bf16* g0 = gx + (long)(tn_ * 16 + b) * 2688 + col0 + c2;
#pragma unroll
            for (int g = 0; g < 3; ++g) {
                gxv[g * 2 + 0] = (float)g0[g * 896 + 0];
                gxv[g * 2 + 1] = (float)g0[g * 896 + 1];
            }
        }
    }
}

extern "C" void kernel_launch(void* const* d_in, const int* in_sizes, int n_in,
                              void* d_out, int out_size, void* d_ws, size_t ws_size,
                              hipStream_t stream)
{
    const int*   samp = (const int*)d_in[0];
    const float* cnd  = (const float*)d_in[1];
    const float* emb  = (const float*)d_in[2];
    const float* Wih  = (const float*)d_in[3];
    const float* bih  = (const float*)d_in[4];
    const float* Whh  = (const float*)d_in[5];
    const float* bhh  = (const float*)d_in[6];
    const float* fc1w = (const float*)d_in[7];
    const float* fc1b = (const float*)d_in[8];
    const float* fc2w = (const float*)d_in[9];
    const float* fc2b = (const float*)d_in[10];

    char* ws = (char*)d_ws;
    unsigned int* flags = (unsigned int*)(ws + FL_OFF);
    bf16* hbuf = (bf16*)(ws + HB_OFF);
    bf16* wbf  = (bf16*)(ws + WBF_OFF);
    bf16* gx   = (bf16*)(ws + GX_OFF);
    bf16* hs   = (bf16*)(ws + HSX_OFF);
    bf16* x    = (bf16*)(ws + HSX_OFF);   // x dead before hs written
    bf16* h1   = (bf16*)(ws + GX_OFF);    // h1 aliases gx (dead after scan)

    bf16* wih_bf = wbf;
    bf16* whh_bf = wbf + W_IH_E;
    bf16* fc1_bf = whh_bf + W_HH_E;
    bf16* fc2_bf = fc1_bf + W_F1_E;

    (void)hipMemsetAsync(flags, 0, 8192, stream);    // barrier flags
    (void)hipMemsetAsync(hbuf, 0, 57344, stream);    // h0 = 0 (both parities)

    // 0) weights f32 -> bf16
    k_cvt<<<1176, 256, 0, stream>>>(Wih,  wih_bf);
    k_cvt<<<1176, 256, 0, stream>>>(Whh,  whh_bf);
    k_cvt<<< 448, 256, 0, stream>>>(fc1w, fc1_bf);
    k_cvt<<< 512, 256, 0, stream>>>(fc2w, fc2_bf);

    // 1) x = concat(emb[sample], cnd)  f32->bf16   [32768, 896]
    k_embed<<<14336, 256, 0, stream>>>(samp, cnd, emb, x);
    // 2) gx = x @ W_ih^T + b_ih  -> [T][B][2688] layout (bf16)
    gemm_bt<0, 1, 0><<<dim3(21, 256), 256, 0, stream>>>(x, wih_bf, bih, gx, 32768, 2688, 896);
    // 3) sequential GRU scan -> hs [B][T][896] (bf16)
    gru_scan<<<NWG, 192, 0, stream>>>(whh_bf, bhh, gx, hs, hbuf, flags);
    // 4) h1 = relu(hs @ fc1_w^T + fc1_b)           [32768, 1024] (bf16)
    gemm_bt<1, 0, 0><<<dim3(8, 256), 256, 0, stream>>>(hs, fc1_bf, fc1b, h1, 32768, 1024, 896);
    // 5) out = h1 @ fc2_w^T + fc2_b                [32768, 1024] -> f32 d_out
    gemm_bt<0, 0, 1><<<dim3(8, 256), 256, 0, stream>>>(h1, fc2_bf, fc2b, d_out, 32768, 1024, 1024);
}